// Round 5
// baseline (1350.854 us; speedup 1.0000x reference)
//
#include <hip/hip_runtime.h>
#include <hip/hip_bf16.h>
#include <stdint.h>

#define TOKENS 8192
#define DIN    4096
#define DOUT   16384

#define BM 256
#define BN 256
#define BKT 64                 // K per tile
#define NT (DIN / BKT)         // 64 K-tiles
#define NJ (NT / 2)            // 32 iterations, 2 tiles each

typedef short s16x8 __attribute__((ext_vector_type(8)));
typedef float f32x4 __attribute__((ext_vector_type(4)));

#define AS1 __attribute__((address_space(1)))
#define AS3 __attribute__((address_space(3)))
#define VMCNT(n)  asm volatile("s_waitcnt vmcnt(" #n ")" ::: "memory")
#define SCHEDB()  __builtin_amdgcn_sched_barrier(0)
#define BAR()     __builtin_amdgcn_s_barrier()

__device__ __forceinline__ unsigned short f2bf(float f) {
  unsigned int u = __float_as_uint(f);
  u += 0x7fffu + ((u >> 16) & 1u);   // round-to-nearest-even
  return (unsigned short)(u >> 16);
}

// -------- Kernel 1: LayerNorm fp32 -> bf16
__global__ __launch_bounds__(256) void ln_kernel(const float* __restrict__ x,
                                                 unsigned short* __restrict__ xn) {
  const int row = blockIdx.x;
  const float4* xr = reinterpret_cast<const float4*>(x + (size_t)row * DIN);
  float4 v[4];
  float sum = 0.f, ssq = 0.f;
#pragma unroll
  for (int i = 0; i < 4; ++i) {
    v[i] = xr[threadIdx.x + i * 256];
    sum += v[i].x + v[i].y + v[i].z + v[i].w;
    ssq += v[i].x * v[i].x + v[i].y * v[i].y + v[i].z * v[i].z + v[i].w * v[i].w;
  }
#pragma unroll
  for (int off = 32; off > 0; off >>= 1) {
    sum += __shfl_xor(sum, off, 64);
    ssq += __shfl_xor(ssq, off, 64);
  }
  __shared__ float red[8];
  const int wid = threadIdx.x >> 6;
  if ((threadIdx.x & 63) == 0) { red[wid] = sum; red[wid + 4] = ssq; }
  __syncthreads();
  sum = red[0] + red[1] + red[2] + red[3];
  ssq = red[4] + red[5] + red[6] + red[7];
  const float mean = sum * (1.f / DIN);
  const float var  = ssq * (1.f / DIN) - mean * mean;
  const float rs   = rsqrtf(var + 1e-5f);
  ushort4* xo = reinterpret_cast<ushort4*>(xn + (size_t)row * DIN);
#pragma unroll
  for (int i = 0; i < 4; ++i) {
    ushort4 o;
    o.x = f2bf((v[i].x - mean) * rs);
    o.y = f2bf((v[i].y - mean) * rs);
    o.z = f2bf((v[i].z - mean) * rs);
    o.w = f2bf((v[i].w - mean) * rs);
    xo[threadIdx.x + i * 256] = o;
  }
}

// -------- Kernel 2: W fp32 -> bf16
__global__ __launch_bounds__(256) void cvt_kernel(const float* __restrict__ W,
                                                  unsigned short* __restrict__ Wb) {
  const size_t i = (size_t)blockIdx.x * 256 + threadIdx.x;
  float4 v = reinterpret_cast<const float4*>(W)[i];
  ushort4 o;
  o.x = f2bf(v.x); o.y = f2bf(v.y); o.z = f2bf(v.z); o.w = f2bf(v.w);
  reinterpret_cast<ushort4*>(Wb)[i] = o;
}

// -------- Kernel 3: C = sigmoid(A @ B^T), 8-phase 256x256, quarter-staged.
// 8 waves (2x4), wave tile 128x64, BK=64, dbuf LDS (128 KiB).
// k-split phases: ph1:(m0-3,k0) ph2:(m0-3,k1) ph3:(m4-7,k0) ph4:(m4-7,k1)
// for buf0, ph5-8 same for buf1. B frags (both k) persist in regs 4 phases.
// Reads/phase: 8/8/4/4 b128. Stages/phase: [2,0,6,0,2,0,6,0] quarters' loads;
// every quarter staged exactly 6 phases before first read; any 4-phase stage
// window sums to 8 -> vmcnt(8) at each phase top confirms (issuer) every
// needed quarter by phase p-1, published by p-1's closing barrier.
__global__ __launch_bounds__(512, 2) void gemm_sig(const unsigned short* __restrict__ A,
                                                   const unsigned short* __restrict__ B,
                                                   float* __restrict__ C) {
  __shared__ unsigned short Asl[2 * 256 * 64];  // 64 KB
  __shared__ unsigned short Bsl[2 * 256 * 64];  // 64 KB

  const int bid = blockIdx.x;
  const int cpx = gridDim.x >> 3;
  const int swz = (bid & 7) * cpx + (bid >> 3);
  const int bm = swz & 31;      // TOKENS/BM = 32
  const int bn = swz >> 5;      // DOUT/BN  = 64

  const int tid  = threadIdx.x;
  const int wid  = tid >> 6;
  const int lane = tid & 63;
  const int wr = wid >> 2, wc = wid & 3;

  const unsigned short* gA = A + (size_t)bm * BM * DIN;
  const unsigned short* gB = B + (size_t)bn * BN * DIN;

  // Staging (per quarter = one global_load_lds, 512 lanes x 16B = 8 KB =
  // 64 rows x 128B). Lane l of wave wid writes LDS row wid*8+(l>>3),
  // 16B-slot l&7 (linear dest); fetches global slot (l&7)^(l>>3)
  // (involution swizzle keyed on row&7; R2/R4-validated, 0 conflicts).
  const int l8 = lane >> 3, l7 = lane & 7;
  const int csw = l7 ^ l8;
  const unsigned short* sA = gA + (size_t)(wid * 8 + l8) * DIN + csw * 8;
  const unsigned short* sB = gB + (size_t)(wid * 8 + l8) * DIN + csw * 8;
  const int dOfs = wid * 512;   // ushort units

#define STG_Aq(p, q, kt) __builtin_amdgcn_global_load_lds( \
    (const AS1 void*)(sA + (size_t)(q) * 64 * DIN + (size_t)(kt) * BKT), \
    (AS3 void*)(Asl + ((p) * 256 + (q) * 64) * 64 + dOfs), 16, 0, 0)
#define STG_Bq(p, q, kt) __builtin_amdgcn_global_load_lds( \
    (const AS1 void*)(sB + (size_t)(q) * 64 * DIN + (size_t)(kt) * BKT), \
    (AS3 void*)(Bsl + ((p) * 256 + (q) * 64) * 64 + dOfs), 16, 0, 0)

  // Read side: logical k-slot qk = (lane>>4)+4*kh stored at slot qk^(row&7);
  // row&7 == lane&7 here (row bases are multiples of 8).
  int aO[8], bO[4], slt[2];
#pragma unroll
  for (int m = 0; m < 8; ++m) aO[m] = (wr * 128 + m * 16 + (lane & 15)) * 64;
#pragma unroll
  for (int n = 0; n < 4; ++n) bO[n] = (wc * 64 + n * 16 + (lane & 15)) * 64;
  slt[0] = ((lane >> 4) ^ l7) * 8;
  slt[1] = (((lane >> 4) + 4) ^ l7) * 8;

  s16x8 af[4], bf0[4], bf1[4];
  f32x4 acc[8][4] = {};

#define RD_A(p, mb4, kh) do { _Pragma("unroll") for (int mm = 0; mm < 4; ++mm) \
    af[mm] = *reinterpret_cast<const s16x8*>(Asl + (p) * 16384 + aO[(mb4) + mm] + slt[kh]); } while (0)
#define RD_B(p, kh, dst) do { _Pragma("unroll") for (int nn = 0; nn < 4; ++nn) \
    dst[nn] = *reinterpret_cast<const s16x8*>(Bsl + (p) * 16384 + bO[nn] + slt[kh]); } while (0)
#define MM(mb4, bfr) do { _Pragma("unroll") for (int mm = 0; mm < 4; ++mm) \
    _Pragma("unroll") for (int nn = 0; nn < 4; ++nn) \
      acc[(mb4) + mm][nn] = __builtin_amdgcn_mfma_f32_16x16x32_bf16(af[mm], bfr[nn], acc[(mb4) + mm][nn], 0, 0, 0); } while (0)
#define PRIO1() __builtin_amdgcn_s_setprio(1)
#define PRIO0() __builtin_amdgcn_s_setprio(0)

  // Prologue: t0 full (8 loads), then t1: A q0,q2 + B all (6 loads).
  STG_Aq(0, 0, 0); STG_Aq(0, 1, 0); STG_Aq(0, 2, 0); STG_Aq(0, 3, 0);
  STG_Bq(0, 0, 0); STG_Bq(0, 1, 0); STG_Bq(0, 2, 0); STG_Bq(0, 3, 0);
  STG_Aq(1, 0, 1); STG_Aq(1, 2, 1);
  STG_Bq(1, 0, 1); STG_Bq(1, 1, 1); STG_Bq(1, 2, 1); STG_Bq(1, 3, 1);
  VMCNT(6); SCHEDB(); BAR();

  for (int j = 0; j < NJ - 1; ++j) {
    const int t1 = 2 * j + 1, t2 = 2 * j + 2, t3 = 2 * j + 3;
    // ph1: buf0 (m0-3,k0); stage A1 q1,q3 <- t1
    VMCNT(8); RD_A(0, 0, 0); RD_B(0, 0, bf0);
    STG_Aq(1, 1, t1); STG_Aq(1, 3, t1);
    SCHEDB(); BAR(); PRIO1(); MM(0, bf0); PRIO0(); SCHEDB(); BAR();
    // ph2: (m0-3,k1)
    VMCNT(8); RD_A(0, 0, 1); RD_B(0, 1, bf1);
    SCHEDB(); BAR(); PRIO1(); MM(0, bf1); PRIO0(); SCHEDB(); BAR();
    // ph3: (m4-7,k0); stage B0 all + A0 q0,q2 <- t2
    VMCNT(8); RD_A(0, 4, 0);
    STG_Bq(0, 0, t2); STG_Bq(0, 1, t2); STG_Bq(0, 2, t2); STG_Bq(0, 3, t2);
    STG_Aq(0, 0, t2); STG_Aq(0, 2, t2);
    SCHEDB(); BAR(); PRIO1(); MM(4, bf0); PRIO0(); SCHEDB(); BAR();
    // ph4: (m4-7,k1)
    VMCNT(8); RD_A(0, 4, 1);
    SCHEDB(); BAR(); PRIO1(); MM(4, bf1); PRIO0(); SCHEDB(); BAR();
    // ph5: buf1 (m0-3,k0); stage A0 q1,q3 <- t2
    VMCNT(8); RD_A(1, 0, 0); RD_B(1, 0, bf0);
    STG_Aq(0, 1, t2); STG_Aq(0, 3, t2);
    SCHEDB(); BAR(); PRIO1(); MM(0, bf0); PRIO0(); SCHEDB(); BAR();
    // ph6: (m0-3,k1)
    VMCNT(8); RD_A(1, 0, 1); RD_B(1, 1, bf1);
    SCHEDB(); BAR(); PRIO1(); MM(0, bf1); PRIO0(); SCHEDB(); BAR();
    // ph7: (m4-7,k0); stage B1 all + A1 q0,q2 <- t3
    VMCNT(8); RD_A(1, 4, 0);
    STG_Bq(1, 0, t3); STG_Bq(1, 1, t3); STG_Bq(1, 2, t3); STG_Bq(1, 3, t3);
    STG_Aq(1, 0, t3); STG_Aq(1, 2, t3);
    SCHEDB(); BAR(); PRIO1(); MM(4, bf0); PRIO0(); SCHEDB(); BAR();
    // ph8: (m4-7,k1)
    VMCNT(8); RD_A(1, 4, 1);
    SCHEDB(); BAR(); PRIO1(); MM(4, bf1); PRIO0(); SCHEDB(); BAR();
  }

  // Last iteration (t0 = NT-2, t1 = NT-1): only ph1's stage exists.
  {
    const int t1 = NT - 1;
    VMCNT(8); RD_A(0, 0, 0); RD_B(0, 0, bf0);
    STG_Aq(1, 1, t1); STG_Aq(1, 3, t1);
    SCHEDB(); BAR(); PRIO1(); MM(0, bf0); PRIO0(); SCHEDB(); BAR();
    VMCNT(8); RD_A(0, 0, 1); RD_B(0, 1, bf1);
    SCHEDB(); BAR(); PRIO1(); MM(0, bf1); PRIO0(); SCHEDB(); BAR();
    VMCNT(8); RD_A(0, 4, 0);
    SCHEDB(); BAR(); PRIO1(); MM(4, bf0); PRIO0(); SCHEDB(); BAR();
    VMCNT(2); RD_A(0, 4, 1);   // forces B1/A1q0q2 (staged ph7 prev iter)
    SCHEDB(); BAR(); PRIO1(); MM(4, bf1); PRIO0(); SCHEDB(); BAR();
    VMCNT(2); RD_A(1, 0, 0); RD_B(1, 0, bf0);
    SCHEDB(); BAR(); PRIO1(); MM(0, bf0); PRIO0(); SCHEDB(); BAR();
    VMCNT(0); RD_A(1, 0, 1); RD_B(1, 1, bf1);   // forces ph1's A1 q1,q3
    SCHEDB(); BAR(); PRIO1(); MM(0, bf1); PRIO0(); SCHEDB(); BAR();
    VMCNT(0); RD_A(1, 4, 0);
    SCHEDB(); BAR(); PRIO1(); MM(4, bf0); PRIO0(); SCHEDB(); BAR();
    VMCNT(0); RD_A(1, 4, 1);
    SCHEDB(); BAR(); PRIO1(); MM(4, bf1); PRIO0();
  }

#undef STG_Aq
#undef STG_Bq
#undef RD_A
#undef RD_B
#undef MM

  // Epilogue: C/D layout col = lane&15, row = (lane>>4)*4 + j
  const int crow0 = bm * BM + wr * 128 + (lane >> 4) * 4;
  const int ccol0 = bn * BN + wc * 64 + (lane & 15);
#pragma unroll
  for (int m = 0; m < 8; ++m)
#pragma unroll
    for (int n = 0; n < 4; ++n)
#pragma unroll
      for (int jj = 0; jj < 4; ++jj) {
        const float v = acc[m][n][jj];
        C[(size_t)(crow0 + m * 16 + jj) * DOUT + (ccol0 + n * 16)] = 1.f / (1.f + __expf(-v));
      }
}

extern "C" void kernel_launch(void* const* d_in, const int* in_sizes, int n_in,
                              void* d_out, int out_size, void* d_ws, size_t ws_size,
                              hipStream_t stream) {
  const float* x = (const float*)d_in[0];
  const float* W = (const float*)d_in[1];
  float* out = (float*)d_out;

  unsigned short* xn = (unsigned short*)d_ws;                    // 64 MiB
  unsigned short* Wb = xn + (size_t)TOKENS * DIN;                // 128 MiB

  ln_kernel<<<TOKENS, 256, 0, stream>>>(x, xn);
  cvt_kernel<<<((size_t)DOUT * DIN) / 1024, 256, 0, stream>>>(W, Wb);
  gemm_sig<<<(TOKENS / BM) * (DOUT / BN), 512, 0, stream>>>(xn, Wb, out);
}

// Round 6
// 1337.248 us; speedup vs baseline: 1.0102x; 1.0102x over previous
//
#include <hip/hip_runtime.h>
#include <hip/hip_bf16.h>
#include <stdint.h>

#define TOKENS 8192
#define DIN    4096
#define DOUT   16384

#define BM 256
#define BN 256
#define BKT 64                 // K per tile
#define NT (DIN / BKT)         // 64 K-tiles
#define NJ (NT / 2)            // 32 iterations, 2 tiles each

typedef short s16x8 __attribute__((ext_vector_type(8)));
typedef float f32x4 __attribute__((ext_vector_type(4)));

#define AS1 __attribute__((address_space(1)))
#define AS3 __attribute__((address_space(3)))
#define VMCNT(n)  asm volatile("s_waitcnt vmcnt(" #n ")" ::: "memory")
#define BAR()     __builtin_amdgcn_s_barrier()

__device__ __forceinline__ unsigned short f2bf(float f) {
  unsigned int u = __float_as_uint(f);
  u += 0x7fffu + ((u >> 16) & 1u);   // round-to-nearest-even
  return (unsigned short)(u >> 16);
}

// -------- Kernel 1: LayerNorm fp32 -> bf16
__global__ __launch_bounds__(256) void ln_kernel(const float* __restrict__ x,
                                                 unsigned short* __restrict__ xn) {
  const int row = blockIdx.x;
  const float4* xr = reinterpret_cast<const float4*>(x + (size_t)row * DIN);
  float4 v[4];
  float sum = 0.f, ssq = 0.f;
#pragma unroll
  for (int i = 0; i < 4; ++i) {
    v[i] = xr[threadIdx.x + i * 256];
    sum += v[i].x + v[i].y + v[i].z + v[i].w;
    ssq += v[i].x * v[i].x + v[i].y * v[i].y + v[i].z * v[i].z + v[i].w * v[i].w;
  }
#pragma unroll
  for (int off = 32; off > 0; off >>= 1) {
    sum += __shfl_xor(sum, off, 64);
    ssq += __shfl_xor(ssq, off, 64);
  }
  __shared__ float red[8];
  const int wid = threadIdx.x >> 6;
  if ((threadIdx.x & 63) == 0) { red[wid] = sum; red[wid + 4] = ssq; }
  __syncthreads();
  sum = red[0] + red[1] + red[2] + red[3];
  ssq = red[4] + red[5] + red[6] + red[7];
  const float mean = sum * (1.f / DIN);
  const float var  = ssq * (1.f / DIN) - mean * mean;
  const float rs   = rsqrtf(var + 1e-5f);
  ushort4* xo = reinterpret_cast<ushort4*>(xn + (size_t)row * DIN);
#pragma unroll
  for (int i = 0; i < 4; ++i) {
    ushort4 o;
    o.x = f2bf((v[i].x - mean) * rs);
    o.y = f2bf((v[i].y - mean) * rs);
    o.z = f2bf((v[i].z - mean) * rs);
    o.w = f2bf((v[i].w - mean) * rs);
    xo[threadIdx.x + i * 256] = o;
  }
}

// -------- Kernel 2: W fp32 -> bf16
__global__ __launch_bounds__(256) void cvt_kernel(const float* __restrict__ W,
                                                  unsigned short* __restrict__ Wb) {
  const size_t i = (size_t)blockIdx.x * 256 + threadIdx.x;
  float4 v = reinterpret_cast<const float4*>(W)[i];
  ushort4 o;
  o.x = f2bf(v.x); o.y = f2bf(v.y); o.z = f2bf(v.z); o.w = f2bf(v.w);
  reinterpret_cast<ushort4*>(Wb)[i] = o;
}

// -------- Kernel 3: C = sigmoid(A @ B^T), 8-phase 256x256, quarter-staged.
// R6 change vs R5: ALL sched_barrier(0) / lgkmcnt(0) fences removed (m141:
// order-pinning costs ~40%). Correctness still holds: VMCNT(8) asm-memory
// clobbers at each phase top contain compiler reordering of LDS ops per
// phase; read->MFMA is data-dependent; cross-wave cases separated by
// s_barrier; HW: ds_read executes at issue, stage LDS-write lands >=900cy
// after issue. Stage pattern [2,0,6,0,2,0,6,0], every quarter has a 5-6
// phase lead to its confirming vmcnt; sliding vmcnt(8) drains only loads
// with >=5-phase age (~1000cy > HBM latency -> near-zero stall).
__global__ __launch_bounds__(512, 2) void gemm_sig(const unsigned short* __restrict__ A,
                                                   const unsigned short* __restrict__ B,
                                                   float* __restrict__ C) {
  __shared__ unsigned short Asl[2 * 256 * 64];  // 64 KB
  __shared__ unsigned short Bsl[2 * 256 * 64];  // 64 KB

  const int bid = blockIdx.x;
  const int cpx = gridDim.x >> 3;
  const int swz = (bid & 7) * cpx + (bid >> 3);
  const int bm = swz & 31;      // TOKENS/BM = 32
  const int bn = swz >> 5;      // DOUT/BN  = 64

  const int tid  = threadIdx.x;
  const int wid  = tid >> 6;
  const int lane = tid & 63;
  const int wr = wid >> 2, wc = wid & 3;

  const unsigned short* gA = A + (size_t)bm * BM * DIN;
  const unsigned short* gB = B + (size_t)bn * BN * DIN;

  // Staging (per quarter = one global_load_lds, 512 lanes x 16B = 8 KB =
  // 64 rows x 128B). Lane l of wave wid writes LDS row wid*8+(l>>3),
  // 16B-slot l&7 (linear dest); fetches global slot (l&7)^(l>>3)
  // (involution swizzle keyed on row&7; validated: 0 bank conflicts).
  const int l8 = lane >> 3, l7 = lane & 7;
  const int csw = l7 ^ l8;
  const unsigned short* sA = gA + (size_t)(wid * 8 + l8) * DIN + csw * 8;
  const unsigned short* sB = gB + (size_t)(wid * 8 + l8) * DIN + csw * 8;
  const int dOfs = wid * 512;   // ushort units

#define STG_Aq(p, q, kt) __builtin_amdgcn_global_load_lds( \
    (const AS1 void*)(sA + (size_t)(q) * 64 * DIN + (size_t)(kt) * BKT), \
    (AS3 void*)(Asl + ((p) * 256 + (q) * 64) * 64 + dOfs), 16, 0, 0)
#define STG_Bq(p, q, kt) __builtin_amdgcn_global_load_lds( \
    (const AS1 void*)(sB + (size_t)(q) * 64 * DIN + (size_t)(kt) * BKT), \
    (AS3 void*)(Bsl + ((p) * 256 + (q) * 64) * 64 + dOfs), 16, 0, 0)

  // Read side: logical k-slot qk = (lane>>4)+4*kh stored at slot qk^(row&7);
  // row&7 == lane&7 here (row bases are multiples of 8).
  int aO[8], bO[4], slt[2];
#pragma unroll
  for (int m = 0; m < 8; ++m) aO[m] = (wr * 128 + m * 16 + (lane & 15)) * 64;
#pragma unroll
  for (int n = 0; n < 4; ++n) bO[n] = (wc * 64 + n * 16 + (lane & 15)) * 64;
  slt[0] = ((lane >> 4) ^ l7) * 8;
  slt[1] = (((lane >> 4) + 4) ^ l7) * 8;

  s16x8 af[4], bf0[4], bf1[4];
  f32x4 acc[8][4] = {};

#define RD_A(p, mb4, kh) do { _Pragma("unroll") for (int mm = 0; mm < 4; ++mm) \
    af[mm] = *reinterpret_cast<const s16x8*>(Asl + (p) * 16384 + aO[(mb4) + mm] + slt[kh]); } while (0)
#define RD_B(p, kh, dst) do { _Pragma("unroll") for (int nn = 0; nn < 4; ++nn) \
    dst[nn] = *reinterpret_cast<const s16x8*>(Bsl + (p) * 16384 + bO[nn] + slt[kh]); } while (0)
#define MM(mb4, bfr) do { _Pragma("unroll") for (int mm = 0; mm < 4; ++mm) \
    _Pragma("unroll") for (int nn = 0; nn < 4; ++nn) \
      acc[(mb4) + mm][nn] = __builtin_amdgcn_mfma_f32_16x16x32_bf16(af[mm], bfr[nn], acc[(mb4) + mm][nn], 0, 0, 0); } while (0)
#define PRIO1() __builtin_amdgcn_s_setprio(1)
#define PRIO0() __builtin_amdgcn_s_setprio(0)

  // Prologue: t0 full (8 loads), then t1: A q0,q2 + B all (6 loads).
  STG_Aq(0, 0, 0); STG_Aq(0, 1, 0); STG_Aq(0, 2, 0); STG_Aq(0, 3, 0);
  STG_Bq(0, 0, 0); STG_Bq(0, 1, 0); STG_Bq(0, 2, 0); STG_Bq(0, 3, 0);
  STG_Aq(1, 0, 1); STG_Aq(1, 2, 1);
  STG_Bq(1, 0, 1); STG_Bq(1, 1, 1); STG_Bq(1, 2, 1); STG_Bq(1, 3, 1);
  VMCNT(6); BAR();

  for (int j = 0; j < NJ - 1; ++j) {
    const int t1 = 2 * j + 1, t2 = 2 * j + 2, t3 = 2 * j + 3;
    // ph1: buf0 (m0-3,k0); stage A1 q1,q3 <- t1
    VMCNT(8); RD_A(0, 0, 0); RD_B(0, 0, bf0);
    STG_Aq(1, 1, t1); STG_Aq(1, 3, t1);
    BAR(); PRIO1(); MM(0, bf0); PRIO0(); BAR();
    // ph2: (m0-3,k1)
    VMCNT(8); RD_A(0, 0, 1); RD_B(0, 1, bf1);
    BAR(); PRIO1(); MM(0, bf1); PRIO0(); BAR();
    // ph3: (m4-7,k0); stage B0 all + A0 q0,q2 <- t2
    VMCNT(8); RD_A(0, 4, 0);
    STG_Bq(0, 0, t2); STG_Bq(0, 1, t2); STG_Bq(0, 2, t2); STG_Bq(0, 3, t2);
    STG_Aq(0, 0, t2); STG_Aq(0, 2, t2);
    BAR(); PRIO1(); MM(4, bf0); PRIO0(); BAR();
    // ph4: (m4-7,k1)
    VMCNT(8); RD_A(0, 4, 1);
    BAR(); PRIO1(); MM(4, bf1); PRIO0(); BAR();
    // ph5: buf1 (m0-3,k0); stage A0 q1,q3 <- t2
    VMCNT(8); RD_A(1, 0, 0); RD_B(1, 0, bf0);
    STG_Aq(0, 1, t2); STG_Aq(0, 3, t2);
    BAR(); PRIO1(); MM(0, bf0); PRIO0(); BAR();
    // ph6: (m0-3,k1)
    VMCNT(8); RD_A(1, 0, 1); RD_B(1, 1, bf1);
    BAR(); PRIO1(); MM(0, bf1); PRIO0(); BAR();
    // ph7: (m4-7,k0); stage B1 all + A1 q0,q2 <- t3
    VMCNT(8); RD_A(1, 4, 0);
    STG_Bq(1, 0, t3); STG_Bq(1, 1, t3); STG_Bq(1, 2, t3); STG_Bq(1, 3, t3);
    STG_Aq(1, 0, t3); STG_Aq(1, 2, t3);
    BAR(); PRIO1(); MM(4, bf0); PRIO0(); BAR();
    // ph8: (m4-7,k1)
    VMCNT(8); RD_A(1, 4, 1);
    BAR(); PRIO1(); MM(4, bf1); PRIO0(); BAR();
  }

  // Last iteration (t0 = NT-2, t1 = NT-1): only ph1's stage exists.
  {
    const int t1 = NT - 1;
    VMCNT(8); RD_A(0, 0, 0); RD_B(0, 0, bf0);
    STG_Aq(1, 1, t1); STG_Aq(1, 3, t1);
    BAR(); PRIO1(); MM(0, bf0); PRIO0(); BAR();
    VMCNT(8); RD_A(0, 0, 1); RD_B(0, 1, bf1);
    BAR(); PRIO1(); MM(0, bf1); PRIO0(); BAR();
    VMCNT(8); RD_A(0, 4, 0);
    BAR(); PRIO1(); MM(4, bf0); PRIO0(); BAR();
    VMCNT(2); RD_A(0, 4, 1);   // forces B1/A1q0q2 (staged ph7 prev iter)
    BAR(); PRIO1(); MM(4, bf1); PRIO0(); BAR();
    VMCNT(2); RD_A(1, 0, 0); RD_B(1, 0, bf0);
    BAR(); PRIO1(); MM(0, bf0); PRIO0(); BAR();
    VMCNT(0); RD_A(1, 0, 1); RD_B(1, 1, bf1);   // forces ph1's A1 q1,q3
    BAR(); PRIO1(); MM(0, bf1); PRIO0(); BAR();
    VMCNT(0); RD_A(1, 4, 0);
    BAR(); PRIO1(); MM(4, bf0); PRIO0(); BAR();
    VMCNT(0); RD_A(1, 4, 1);
    BAR(); PRIO1(); MM(4, bf1); PRIO0();
  }

#undef STG_Aq
#undef STG_Bq
#undef RD_A
#undef RD_B
#undef MM

  // Epilogue: C/D layout col = lane&15, row = (lane>>4)*4 + j
  const int crow0 = bm * BM + wr * 128 + (lane >> 4) * 4;
  const int ccol0 = bn * BN + wc * 64 + (lane & 15);
#pragma unroll
  for (int m = 0; m < 8; ++m)
#pragma unroll
    for (int n = 0; n < 4; ++n)
#pragma unroll
      for (int jj = 0; jj < 4; ++jj) {
        const float v = acc[m][n][jj];
        C[(size_t)(crow0 + m * 16 + jj) * DOUT + (ccol0 + n * 16)] = 1.f / (1.f + __expf(-v));
      }
}

extern "C" void kernel_launch(void* const* d_in, const int* in_sizes, int n_in,
                              void* d_out, int out_size, void* d_ws, size_t ws_size,
                              hipStream_t stream) {
  const float* x = (const float*)d_in[0];
  const float* W = (const float*)d_in[1];
  float* out = (float*)d_out;

  unsigned short* xn = (unsigned short*)d_ws;                    // 64 MiB
  unsigned short* Wb = xn + (size_t)TOKENS * DIN;                // 128 MiB

  ln_kernel<<<TOKENS, 256, 0, stream>>>(x, xn);
  cvt_kernel<<<((size_t)DOUT * DIN) / 1024, 256, 0, stream>>>(W, Wb);
  gemm_sig<<<(TOKENS / BM) * (DOUT / BN), 512, 0, stream>>>(xn, Wb, out);
}

// Round 7
// 1282.953 us; speedup vs baseline: 1.0529x; 1.0423x over previous
//
#include <hip/hip_runtime.h>
#include <hip/hip_bf16.h>
#include <stdint.h>

#define TOKENS 8192
#define DIN    4096
#define DOUT   16384

#define BM 256
#define BN 256
#define BKT 64                 // K per tile
#define NT (DIN / BKT)         // 64 K-tiles
#define NJ (NT / 2)            // 32 iterations, 2 tiles each

typedef short s16x8 __attribute__((ext_vector_type(8)));
typedef float f32x4 __attribute__((ext_vector_type(4)));

#define AS1 __attribute__((address_space(1)))
#define AS3 __attribute__((address_space(3)))
#define VMCNT(n)  asm volatile("s_waitcnt vmcnt(" #n ")" ::: "memory")
#define BAR()     __builtin_amdgcn_s_barrier()

__device__ __forceinline__ unsigned short f2bf(float f) {
  unsigned int u = __float_as_uint(f);
  u += 0x7fffu + ((u >> 16) & 1u);   // round-to-nearest-even
  return (unsigned short)(u >> 16);
}

// -------- Kernel 1: LayerNorm fp32 -> bf16
__global__ __launch_bounds__(256) void ln_kernel(const float* __restrict__ x,
                                                 unsigned short* __restrict__ xn) {
  const int row = blockIdx.x;
  const float4* xr = reinterpret_cast<const float4*>(x + (size_t)row * DIN);
  float4 v[4];
  float sum = 0.f, ssq = 0.f;
#pragma unroll
  for (int i = 0; i < 4; ++i) {
    v[i] = xr[threadIdx.x + i * 256];
    sum += v[i].x + v[i].y + v[i].z + v[i].w;
    ssq += v[i].x * v[i].x + v[i].y * v[i].y + v[i].z * v[i].z + v[i].w * v[i].w;
  }
#pragma unroll
  for (int off = 32; off > 0; off >>= 1) {
    sum += __shfl_xor(sum, off, 64);
    ssq += __shfl_xor(ssq, off, 64);
  }
  __shared__ float red[8];
  const int wid = threadIdx.x >> 6;
  if ((threadIdx.x & 63) == 0) { red[wid] = sum; red[wid + 4] = ssq; }
  __syncthreads();
  sum = red[0] + red[1] + red[2] + red[3];
  ssq = red[4] + red[5] + red[6] + red[7];
  const float mean = sum * (1.f / DIN);
  const float var  = ssq * (1.f / DIN) - mean * mean;
  const float rs   = rsqrtf(var + 1e-5f);
  ushort4* xo = reinterpret_cast<ushort4*>(xn + (size_t)row * DIN);
#pragma unroll
  for (int i = 0; i < 4; ++i) {
    ushort4 o;
    o.x = f2bf((v[i].x - mean) * rs);
    o.y = f2bf((v[i].y - mean) * rs);
    o.z = f2bf((v[i].z - mean) * rs);
    o.w = f2bf((v[i].w - mean) * rs);
    xo[threadIdx.x + i * 256] = o;
  }
}

// -------- Kernel 2: W fp32 -> bf16
__global__ __launch_bounds__(256) void cvt_kernel(const float* __restrict__ W,
                                                  unsigned short* __restrict__ Wb) {
  const size_t i = (size_t)blockIdx.x * 256 + threadIdx.x;
  float4 v = reinterpret_cast<const float4*>(W)[i];
  ushort4 o;
  o.x = f2bf(v.x); o.y = f2bf(v.y); o.z = f2bf(v.z); o.w = f2bf(v.w);
  reinterpret_cast<ushort4*>(Wb)[i] = o;
}

// -------- Kernel 3: C = sigmoid(A @ B^T), 8-phase 256x256, quarter-staged.
// R7 change vs R6: REGISTER-LEVEL FRAGMENT PIPELINING. Each phase's ds_reads
// load the NEXT phase's fragments (afX/afY ping-pong for A; bf0/bf1 for B,
// 4-phase lifetime). The LDS read-burst of phase p drains DURING phase p's
// MFMA cluster; the compiler's counted lgkmcnt only waits for the previous
// phase's (already-drained) reads. Pipe math: LDS ~700 cyc/phase, MFMA ~620;
// overlapped -> MfmaUtil ceiling ~62% vs the serialized 38% of R4-R6.
// Hazards re-verified: reg read->consume = 1 phase; LDS region last-read ->
// re-stage >= 2 barrier-separated phases; stage -> first-read = 5 phases
// confirmed by sliding VMCNT(8); exact drains in tail iter.
__global__ __launch_bounds__(512, 2) void gemm_sig(const unsigned short* __restrict__ A,
                                                   const unsigned short* __restrict__ B,
                                                   float* __restrict__ C) {
  __shared__ unsigned short Asl[2 * 256 * 64];  // 64 KB
  __shared__ unsigned short Bsl[2 * 256 * 64];  // 64 KB

  const int bid = blockIdx.x;
  const int cpx = gridDim.x >> 3;
  const int swz = (bid & 7) * cpx + (bid >> 3);
  const int bm = swz & 31;      // TOKENS/BM = 32
  const int bn = swz >> 5;      // DOUT/BN  = 64

  const int tid  = threadIdx.x;
  const int wid  = tid >> 6;
  const int lane = tid & 63;
  const int wr = wid >> 2, wc = wid & 3;

  const unsigned short* gA = A + (size_t)bm * BM * DIN;
  const unsigned short* gB = B + (size_t)bn * BN * DIN;

  // Staging (per quarter = one global_load_lds, 512 lanes x 16B = 8 KB =
  // 64 rows x 128B). Lane l of wave wid writes LDS row wid*8+(l>>3),
  // 16B-slot l&7 (linear dest); fetches global slot (l&7)^(l>>3)
  // (involution swizzle keyed on row&7; validated: 0 bank conflicts).
  const int l8 = lane >> 3, l7 = lane & 7;
  const int csw = l7 ^ l8;
  const unsigned short* sA = gA + (size_t)(wid * 8 + l8) * DIN + csw * 8;
  const unsigned short* sB = gB + (size_t)(wid * 8 + l8) * DIN + csw * 8;
  const int dOfs = wid * 512;   // ushort units

#define STG_Aq(p, q, kt) __builtin_amdgcn_global_load_lds( \
    (const AS1 void*)(sA + (size_t)(q) * 64 * DIN + (size_t)(kt) * BKT), \
    (AS3 void*)(Asl + ((p) * 256 + (q) * 64) * 64 + dOfs), 16, 0, 0)
#define STG_Bq(p, q, kt) __builtin_amdgcn_global_load_lds( \
    (const AS1 void*)(sB + (size_t)(q) * 64 * DIN + (size_t)(kt) * BKT), \
    (AS3 void*)(Bsl + ((p) * 256 + (q) * 64) * 64 + dOfs), 16, 0, 0)

  // Read side: logical k-slot qk = (lane>>4)+4*kh stored at slot qk^(row&7);
  // row&7 == lane&7 here (row bases are multiples of 8).
  int aO[8], bO[4], slt[2];
#pragma unroll
  for (int m = 0; m < 8; ++m) aO[m] = (wr * 128 + m * 16 + (lane & 15)) * 64;
#pragma unroll
  for (int n = 0; n < 4; ++n) bO[n] = (wc * 64 + n * 16 + (lane & 15)) * 64;
  slt[0] = ((lane >> 4) ^ l7) * 8;
  slt[1] = (((lane >> 4) + 4) ^ l7) * 8;

  s16x8 afX[4], afY[4], bf0[4], bf1[4];
  f32x4 acc[8][4] = {};

#define RD_A(p, mb4, kh, dst) do { _Pragma("unroll") for (int mm = 0; mm < 4; ++mm) \
    dst[mm] = *reinterpret_cast<const s16x8*>(Asl + (p) * 16384 + aO[(mb4) + mm] + slt[kh]); } while (0)
#define RD_B(p, kh, dst) do { _Pragma("unroll") for (int nn = 0; nn < 4; ++nn) \
    dst[nn] = *reinterpret_cast<const s16x8*>(Bsl + (p) * 16384 + bO[nn] + slt[kh]); } while (0)
#define MM(mb4, afr, bfr) do { _Pragma("unroll") for (int mm = 0; mm < 4; ++mm) \
    _Pragma("unroll") for (int nn = 0; nn < 4; ++nn) \
      acc[(mb4) + mm][nn] = __builtin_amdgcn_mfma_f32_16x16x32_bf16(afr[mm], bfr[nn], acc[(mb4) + mm][nn], 0, 0, 0); } while (0)
#define PRIO1() __builtin_amdgcn_s_setprio(1)
#define PRIO0() __builtin_amdgcn_s_setprio(0)

  // Prologue: t0 full (8 loads), then t1: A q0,q2 + B all (6 loads).
  STG_Aq(0, 0, 0); STG_Aq(0, 1, 0); STG_Aq(0, 2, 0); STG_Aq(0, 3, 0);
  STG_Bq(0, 0, 0); STG_Bq(0, 1, 0); STG_Bq(0, 2, 0); STG_Bq(0, 3, 0);
  STG_Aq(1, 0, 1); STG_Aq(1, 2, 1);
  STG_Bq(1, 0, 1); STG_Bq(1, 1, 1); STG_Bq(1, 2, 1); STG_Bq(1, 3, 1);
  VMCNT(6); BAR();
  // Pre-load ph1's fragments (buf0, k0).
  RD_A(0, 0, 0, afX); RD_B(0, 0, bf0);

  for (int j = 0; j < NJ - 1; ++j) {
    const int t1 = 2 * j + 1, t2 = 2 * j + 2, t3 = 2 * j + 3;
    // ph1: MFMA(m0-3 x bf0)[afX]; reads->afY:A(0,m0-3,k1), bf1:B(0,k1); stage A1q1q3<-t1
    VMCNT(8); RD_A(0, 0, 1, afY); RD_B(0, 1, bf1);
    STG_Aq(1, 1, t1); STG_Aq(1, 3, t1);
    BAR(); PRIO1(); MM(0, afX, bf0); PRIO0(); BAR();
    // ph2: MFMA(m0-3 x bf1)[afY]; reads->afX:A(0,m4-7,k0)
    VMCNT(8); RD_A(0, 4, 0, afX);
    BAR(); PRIO1(); MM(0, afY, bf1); PRIO0(); BAR();
    // ph3: MFMA(m4-7 x bf0)[afX]; reads->afY:A(0,m4-7,k1); stage B0 all + A0q0q2 <- t2
    VMCNT(8); RD_A(0, 4, 1, afY);
    STG_Bq(0, 0, t2); STG_Bq(0, 1, t2); STG_Bq(0, 2, t2); STG_Bq(0, 3, t2);
    STG_Aq(0, 0, t2); STG_Aq(0, 2, t2);
    BAR(); PRIO1(); MM(4, afX, bf0); PRIO0(); BAR();
    // ph4: MFMA(m4-7 x bf1)[afY]; reads->afX:A(1,m0-3,k0), bf0:B(1,k0)
    VMCNT(8); RD_A(1, 0, 0, afX); RD_B(1, 0, bf0);
    BAR(); PRIO1(); MM(4, afY, bf1); PRIO0(); BAR();
    // ph5: MFMA(m0-3 x bf0)[afX, buf1]; reads->afY:A(1,m0-3,k1), bf1:B(1,k1); stage A0q1q3<-t2
    VMCNT(8); RD_A(1, 0, 1, afY); RD_B(1, 1, bf1);
    STG_Aq(0, 1, t2); STG_Aq(0, 3, t2);
    BAR(); PRIO1(); MM(0, afX, bf0); PRIO0(); BAR();
    // ph6: MFMA(m0-3 x bf1)[afY]; reads->afX:A(1,m4-7,k0)
    VMCNT(8); RD_A(1, 4, 0, afX);
    BAR(); PRIO1(); MM(0, afY, bf1); PRIO0(); BAR();
    // ph7: MFMA(m4-7 x bf0)[afX]; reads->afY:A(1,m4-7,k1); stage B1 all + A1q0q2 <- t3
    VMCNT(8); RD_A(1, 4, 1, afY);
    STG_Bq(1, 0, t3); STG_Bq(1, 1, t3); STG_Bq(1, 2, t3); STG_Bq(1, 3, t3);
    STG_Aq(1, 0, t3); STG_Aq(1, 2, t3);
    BAR(); PRIO1(); MM(4, afX, bf0); PRIO0(); BAR();
    // ph8: MFMA(m4-7 x bf1)[afY]; reads->afX:A(0,m0-3,k0)[next buf0], bf0:B(0,k0)[next]
    VMCNT(8); RD_A(0, 0, 0, afX); RD_B(0, 0, bf0);
    BAR(); PRIO1(); MM(4, afY, bf1); PRIO0(); BAR();
  }

  // Last iteration (t0 = NT-2 in buf0, t1 = NT-1 in buf1): only ph1's stage.
  {
    const int t1 = NT - 1;
    VMCNT(8); RD_A(0, 0, 1, afY); RD_B(0, 1, bf1);
    STG_Aq(1, 1, t1); STG_Aq(1, 3, t1);
    BAR(); PRIO1(); MM(0, afX, bf0); PRIO0(); BAR();
    VMCNT(8); RD_A(0, 4, 0, afX);          // A0 q1q3: forced by this vmcnt (ph5-prev loads)
    BAR(); PRIO1(); MM(0, afY, bf1); PRIO0(); BAR();
    VMCNT(8); RD_A(0, 4, 1, afY);
    BAR(); PRIO1(); MM(4, afX, bf0); PRIO0(); BAR();
    VMCNT(2); RD_A(1, 0, 0, afX); RD_B(1, 0, bf0);   // forces B1/A1q0q2 (ph7-prev)
    BAR(); PRIO1(); MM(4, afY, bf1); PRIO0(); BAR();
    VMCNT(2); RD_A(1, 0, 1, afY); RD_B(1, 1, bf1);
    BAR(); PRIO1(); MM(0, afX, bf0); PRIO0(); BAR();
    VMCNT(0); RD_A(1, 4, 0, afX);          // forces ph1's A1 q1,q3
    BAR(); PRIO1(); MM(0, afY, bf1); PRIO0(); BAR();
    VMCNT(0); RD_A(1, 4, 1, afY);
    BAR(); PRIO1(); MM(4, afX, bf0); PRIO0(); BAR();
    PRIO1(); MM(4, afY, bf1); PRIO0();
  }

#undef STG_Aq
#undef STG_Bq
#undef RD_A
#undef RD_B
#undef MM

  // Epilogue: C/D layout col = lane&15, row = (lane>>4)*4 + j
  const int crow0 = bm * BM + wr * 128 + (lane >> 4) * 4;
  const int ccol0 = bn * BN + wc * 64 + (lane & 15);
#pragma unroll
  for (int m = 0; m < 8; ++m)
#pragma unroll
    for (int n = 0; n < 4; ++n)
#pragma unroll
      for (int jj = 0; jj < 4; ++jj) {
        const float v = acc[m][n][jj];
        C[(size_t)(crow0 + m * 16 + jj) * DOUT + (ccol0 + n * 16)] = 1.f / (1.f + __expf(-v));
      }
}

extern "C" void kernel_launch(void* const* d_in, const int* in_sizes, int n_in,
                              void* d_out, int out_size, void* d_ws, size_t ws_size,
                              hipStream_t stream) {
  const float* x = (const float*)d_in[0];
  const float* W = (const float*)d_in[1];
  float* out = (float*)d_out;

  unsigned short* xn = (unsigned short*)d_ws;                    // 64 MiB
  unsigned short* Wb = xn + (size_t)TOKENS * DIN;                // 128 MiB

  ln_kernel<<<TOKENS, 256, 0, stream>>>(x, xn);
  cvt_kernel<<<((size_t)DOUT * DIN) / 1024, 256, 0, stream>>>(W, Wb);
  gemm_sig<<<(TOKENS / BM) * (DOUT / BN), 512, 0, stream>>>(xn, Wb, out);
}